// Round 9
// baseline (11910.150 us; speedup 1.0000x reference)
//
#include <hip/hip_runtime.h>

// Seq2Seq LSTM H=128: enc 8192 + dec 4096 strictly sequential steps.
// Single block, one CU. R17: 256 threads (4 waves, 1 wave/SIMD).
//
// R16 post-mortem: conflicts hit the 2-way floor (1.57M, identical to
// R7-R10 across 3 layouts) -> LDS-conflict lever exhausted. Budget
// 990 cyc/step = ~520 issue + ~200 chain + ~75 barrier.
//
// R17: halve the wave count. pk_fma floor is wave-invariant (256
// cyc/SIMD) but per-wave overhead (rdlane/loads/stores/nonlin) halves.
//  * 4 waves x 32-wide j-slice (16 pairs): 128 pk_fma/lane; weights
//    w2[8][16] = 256 VGPR -- legal at 1 wave/SIMD (launch_bounds 256,1).
//  * Exchange: 4 partials/row (LDS traffic halved). slot = 512wv+row.
//    Writer banks lane%32 2-way; reader: lane l reduces rows
//    r0 = 128*(l&1) + u, r1 = r0+256 (u = 32wv+(l>>1)), banks u%32
//    2-way. 8x ds_read_b32 + 6-add tree.
//  * Lane computes TWO gates (even: i,g; odd: f,o of unit u);
//    qperm<0xB1> pair-swap + 4 selects rebuilds (i,f,g,o) in both
//    lanes; cst/hn replicated per pair. h stays in-register:
//    h[32wv+u'] in lanes 2u'/2u'+1 -> rdlane(hn, 4jj / 4jj+2).
//  * v0 (i or f) is ALWAYS sigmoid (uniform constants); v1 keyed on
//    lane parity (even->tanh for g, odd->sigmoid for o).
// Kept: s-pair pk_fma/pk_mul, exp2-folded nonlin, post-barrier OUTBLK
// (wave 3), 2-step parity unroll, one barrier/step.

#define H      128
#define ENC_T  8192
#define DEC_T  4096
#define NT     256
#define NBLK   1
#define PBUF   2048         // 4 waves * 512 rows

#define LOG2E  1.4426950408889634f

typedef float v2f __attribute__((ext_vector_type(2)));

__device__ __forceinline__ v2f pk_fma_s(v2f a, v2f b_sgpr, v2f c) {
    v2f d;   // b is wave-uniform: read as 64-bit scalar operand (s-pair)
    asm("v_pk_fma_f32 %0, %1, %2, %3" : "=v"(d) : "v"(a), "s"(b_sgpr), "v"(c));
    return d;
}
__device__ __forceinline__ v2f pk_mul_s(v2f a, v2f b_sgpr) {
    v2f d;   // first-iteration accumulator: acc = w*h (no zero-init)
    asm("v_pk_mul_f32 %0, %1, %2" : "=v"(d) : "v"(a), "s"(b_sgpr));
    return d;
}
__device__ __forceinline__ v2f pk_fma(v2f a, v2f b, v2f c) {
    v2f d;
    asm("v_pk_fma_f32 %0, %1, %2, %3" : "=v"(d) : "v"(a), "v"(b), "v"(c));
    return d;
}
__device__ __forceinline__ float exp2fast(float x) {   // raw v_exp_f32 (2^x)
    float d;
    asm("v_exp_f32 %0, %1" : "=v"(d) : "v"(x));
    return d;
}
__device__ __forceinline__ float tanhfast(float x) {   // 1 - 2/(1+2^(2*log2e*x))
    const float e = exp2fast(2.0f * LOG2E * x);
    return fmaf(-2.0f, __builtin_amdgcn_rcpf(1.0f + e), 1.0f);
}
__device__ __forceinline__ float rdlane(float v, int l) {
    return __int_as_float(__builtin_amdgcn_readlane(__float_as_int(v), l));
}
template <int CTRL>
__device__ __forceinline__ float qperm(float v) {      // DPP quad_perm, VALU-speed
    return __int_as_float(
        __builtin_amdgcn_mov_dpp(__float_as_int(v), CTRL, 0xf, 0xf, true));
}

__global__ __launch_bounds__(NT, 1)
void seq2seq_lstm(const float* __restrict__ input_seq,
                  const float* __restrict__ enc_Wih,
                  const float* __restrict__ enc_Whh,
                  const float* __restrict__ enc_bih,
                  const float* __restrict__ enc_bhh,
                  const float* __restrict__ dec_Wih,
                  const float* __restrict__ dec_Whh,
                  const float* __restrict__ dec_bih,
                  const float* __restrict__ dec_bhh,
                  const float* __restrict__ fc_W,
                  const float* __restrict__ fc_b,
                  float* __restrict__ out,
                  unsigned* __restrict__ wsflag)
{
    (void)wsflag;
    __shared__ __align__(16) float xin[ENC_T];          // 32 KB
    __shared__ __align__(16) float hbuf[2][H];          // h history (off-path)
    __shared__ __align__(16) float part[2][PBUF];       // dbl-buffered partials

    const int t    = threadIdx.x;      // 0..255
    const int lane = t & 63;
    const int wv   = t >> 6;           // wave 0..3, j-slice [32wv, 32wv+32)
    const int jb   = 32 * wv;
    const int u    = jb + (lane >> 1); // my unit (pair-replicated)
    const bool ev  = (lane & 1) == 0;
    const int r0   = 128 * (lane & 1) + u;   // even: i-row u; odd: f-row 128+u
    const int r1   = r0 + 256;               // even: g-row;   odd: o-row
    const int wbase = 512 * wv + lane;       // writer slot base

    // v1 nonlin constants: even lane -> tanh (gate g), odd -> sigmoid (o)
    const float sA  = ev ? 1.0f : 0.0f;
    const float sB  = ev ? -2.0f : 1.0f;
    const float sS2 = (ev ? 2.0f : -1.0f) * LOG2E;

    {   // stage input sequence
        const float4* s = (const float4*)input_seq;
        float4* d = (float4*)xin;
        for (int i = t; i < ENC_T / 4; i += NT) d[i] = s[i];
    }

    // weights as j-pairs: w2[s][jj] = Whh[(64s+lane)][jb+2jj, jb+2jj+1]
    v2f w2[8][16];
#pragma unroll
    for (int s = 0; s < 8; ++s) {
        const v2f* Wr = (const v2f*)(enc_Whh + (64 * s + lane) * H + jb);
#pragma unroll
        for (int jj = 0; jj < 16; ++jj) w2[s][jj] = Wr[jj];
    }
    float bias0 = enc_bih[r0] + enc_bhh[r0];
    float bias1 = enc_bih[r1] + enc_bhh[r1];
    float wih0  = enc_Wih[r0];
    float wih1  = enc_Wih[r1];

    float cst = 0.f;      // cell state of unit u (replicated per lane-pair)
    float hn  = 0.f;      // h of unit u (replicated per lane-pair)
    __syncthreads();

    // h[jb+2jj]   lives in lanes 4jj,4jj+1 -> rdlane(hn, 4jj)
    // h[jb+2jj+1] lives in lanes 4jj+2,4jj+3 -> rdlane(hn, 4jj+2)
    // row 64s+lane -> slot wbase + 64s
#define MATVEC(PB)                                                          \
    {                                                                       \
        v2f acc2[8];                                                        \
        {   /* jj = 0: pk_mul, no accumulator init */                       \
            const float se = rdlane(hn, 0);                                 \
            const float so = rdlane(hn, 2);                                 \
            const v2f hp = {se, so};                                        \
            _Pragma("unroll") for (int s = 0; s < 8; ++s)                   \
                acc2[s] = pk_mul_s(w2[s][0], hp);                           \
        }                                                                   \
        _Pragma("unroll") for (int jj = 1; jj < 16; ++jj) {                 \
            const float se = rdlane(hn, 4 * jj);                            \
            const float so = rdlane(hn, 4 * jj + 2);                        \
            const v2f hp = {se, so};                                        \
            _Pragma("unroll") for (int s = 0; s < 8; ++s)                   \
                acc2[s] = pk_fma_s(w2[s][jj], hp, acc2[s]);                 \
        }                                                                   \
        float* pb_ = &part[PB][wbase];                                      \
        _Pragma("unroll") for (int s = 0; s < 8; ++s)                       \
            pb_[64 * s] = acc2[s].x + acc2[s].y;                            \
    }

    // 8x conflict-free ds_read_b32: rows r0 (+0) and r1 (+256), 4 waves
#define RED_LOAD(PB)                                                        \
    const float* rb_ = &part[PB][r0];                                       \
    const float p00_ = rb_[0],    p01_ = rb_[512],                          \
                p02_ = rb_[1024], p03_ = rb_[1536];                         \
    const float p10_ = rb_[256],  p11_ = rb_[768],                          \
                p12_ = rb_[1280], p13_ = rb_[1792];

    // STH: 1 -> store h to hbuf[PB] (decoder out reads stale hbuf)
#define RED_FIN(PB, AB0, AB1, STH)                                          \
    {                                                                       \
        const float a0 = (AB0) + ((p00_ + p01_) + (p02_ + p03_));           \
        const float a1 = (AB1) + ((p10_ + p11_) + (p12_ + p13_));           \
        const float e0 = exp2fast(-LOG2E * a0);                             \
        const float v0 = __builtin_amdgcn_rcpf(1.0f + e0);  /* sigmoid */   \
        const float e1 = exp2fast(sS2 * a1);                                \
        const float v1 = fmaf(sB, __builtin_amdgcn_rcpf(1.0f + e1), sA);    \
        const float s0_ = qperm<0xB1>(v0);   /* pair swap */                \
        const float s1_ = qperm<0xB1>(v1);                                  \
        const float vi = ev ? v0  : s0_;                                    \
        const float vf = ev ? s0_ : v0;                                     \
        const float vg = ev ? v1  : s1_;                                    \
        const float vo = ev ? s1_ : v1;                                     \
        cst = fmaf(vf, cst, vi * vg);                                       \
        hn  = vo * tanhfast(cst);                                           \
        if (STH && ev) hbuf[PB][u] = hn;                                    \
    }

    // post-barrier fc output: out[ST-1] from hbuf[HB] (= h after step ST-1;
    // stable: this step's REDUCE writes hbuf[1-HB]). Runs in wave 3's
    // part-read latency shadow.
#define OUTBLK(ST, HB)                                                      \
    if (wv == 3 && (ST) >= 1) {                                             \
        float p = fmaf(fwl, hbuf[HB][lane], fwh * hbuf[HB][64 + lane]);     \
        p += qperm<0xB1>(p);               /* xor 1 */                      \
        p += qperm<0x4E>(p);               /* xor 2 */                      \
        _Pragma("unroll") for (int m = 32; m >= 4; m >>= 1)                 \
            p += __shfl_xor(p, m, 64);                                      \
        if (lane == 0) out[(ST) - 1] = p + fcb;                             \
    }

    // ---------------- encoder: 8192 steps, ONE barrier each ----------------
    for (int st = 0; st < ENC_T; st += 2) {
        const float2 xx = *(const float2*)&xin[st];
        {
            MATVEC(0);
            __syncthreads();
            RED_LOAD(0);
            RED_FIN(0, fmaf(wih0, xx.x, bias0), fmaf(wih1, xx.x, bias1), 0);
        }
        {
            MATVEC(1);
            __syncthreads();
            RED_LOAD(1);
            RED_FIN(1, fmaf(wih0, xx.y, bias0), fmaf(wih1, xx.y, bias1), 0);
        }
    }
    if (ev) hbuf[1][u] = hn;               // final encoder h, once

    // ---------------- decoder setup: fold fc into Whh ----------------
    const float fcb = fc_b[0];
    const float fwl = fc_W[lane];
    const float fwh = fc_W[64 + lane];
#pragma unroll
    for (int s = 0; s < 8; ++s) {
        const int r = 64 * s + lane;
        const float viw = dec_Wih[r];
        const v2f vip = {viw, viw};
        const v2f* Wr = (const v2f*)(dec_Whh + r * H + jb);
        const v2f* Fr = (const v2f*)(fc_W + jb);
#pragma unroll
        for (int jj = 0; jj < 16; ++jj)
            w2[s][jj] = pk_fma(vip, Fr[jj], Wr[jj]);   // W' = Whh + wih (x) fcW
    }
    wih0  = dec_Wih[r0];
    wih1  = dec_Wih[r1];
    bias0 = dec_bih[r0] + dec_bhh[r0] + wih0 * fcb;
    bias1 = dec_bih[r1] + dec_bhh[r1] + wih1 * fcb;
    __syncthreads();                       // h_enc visible in hbuf[1]
    float q0;
    {   // all waves compute q0 identically
        float p = fmaf(fwl, hbuf[1][lane], fwh * hbuf[1][64 + lane]);
        p += qperm<0xB1>(p);               // xor 1
        p += qperm<0x4E>(p);               // xor 2
#pragma unroll
        for (int m = 32; m >= 4; m >>= 1) p += __shfl_xor(p, m, 64);
        q0 = p + fcb;
    }
    float cb0 = bias0 - wih0 * q0;         // step-0 correction (y0 = 0)
    float cb1 = bias1 - wih1 * q0;

    // ---------------- decoder: 4096 steps ----------------
    for (int st = 0; st < DEC_T; st += 2) {
        {   // even step ST=st: out[st-1] from hbuf[1] (odd-parity h)
            MATVEC(0);
            __syncthreads();
            RED_LOAD(0);
            OUTBLK(st, 1);
            RED_FIN(0, cb0, cb1, 1);
            cb0 = bias0; cb1 = bias1;
        }
        {   // odd step ST=st+1: out[st] from hbuf[0]
            MATVEC(1);
            __syncthreads();
            RED_LOAD(1);
            OUTBLK(st + 1, 0);
            RED_FIN(1, cb0, cb1, 1);
        }
    }

    // tail: out[DEC_T-1] from hbuf[1] (h after final step, parity 1)
    __syncthreads();
    if (wv == 3) {
        float p = fmaf(fwl, hbuf[1][lane], fwh * hbuf[1][64 + lane]);
        p += qperm<0xB1>(p);
        p += qperm<0x4E>(p);
#pragma unroll
        for (int m = 32; m >= 4; m >>= 1) p += __shfl_xor(p, m, 64);
        if (lane == 0) out[DEC_T - 1] = p + fcb;
    }
}

extern "C" void kernel_launch(void* const* d_in, const int* in_sizes, int n_in,
                              void* d_out, int out_size, void* d_ws, size_t ws_size,
                              hipStream_t stream)
{
    (void)in_sizes; (void)n_in; (void)ws_size; (void)out_size;
    seq2seq_lstm<<<NBLK, NT, 0, stream>>>(
        (const float*)d_in[0],   // input_seq
        (const float*)d_in[1],   // enc_Wih
        (const float*)d_in[2],   // enc_Whh
        (const float*)d_in[3],   // enc_bih
        (const float*)d_in[4],   // enc_bhh
        (const float*)d_in[5],   // dec_Wih
        (const float*)d_in[6],   // dec_Whh
        (const float*)d_in[7],   // dec_bih
        (const float*)d_in[8],   // dec_bhh
        (const float*)d_in[9],   // fc_W
        (const float*)d_in[10],  // fc_b
        (float*)d_out,
        (unsigned*)d_ws);
}

// Round 10
// 10344.057 us; speedup vs baseline: 1.1514x; 1.1514x over previous
//
#include <hip/hip_runtime.h>

// Seq2Seq LSTM H=128: enc 8192 + dec 4096 strictly sequential steps.
// Single block, one CU, 512 threads (8 waves). ONE barrier per step.
//
// R18. R17 post-mortem (4-wave, 1 wave/SIMD): VGPR_Count=256 -> gfx950
// plain-VALU code can only address 256 ARCH VGPRs (512 is arch+acc);
// w2[8][16]=256 forced acc-copies/spills in the hot loop. And 1
// wave/SIMD exposes every latency (1570 cyc/step). Wave reduction is
// a DEAD END; reverted to R16 structure (7460 us, 990 cyc/step).
//
// R18 change — raw-v2f exchange (issue-count cut):
//  * Writer: 8x ds_write_b64 of the UNSUMMED v2f accumulators
//    (drops the 8 v_add collapse). slot_v2f = 512wv + 64s + lane;
//    banks = 2*lane mod 32 -> exact 4-way = b64 structural floor.
//  * Reader: 8x ds_read_b64 (slot = 512w + 64sr + lr; banks 2*qq ->
//    4-way floor) + 7x v_pk_add_f32 + 2 scalar adds.
//  * Net -7 instr/lane (~-28 issue cyc/SIMD/step); pipe +~20 hidden.
//  * Sum order: (sum x)+(sum y) - reassociation-robust (R11/R13).
//  * NOTE: SQ_LDS_BANK_CONFLICT may RISE: the 4-way b64 floor is
//    counted by the PMC but costs ~nothing (cf. m136 2-way free; the
//    128/step floor survived 3 layouts). Time is the arbiter.
// Kept: s-pair pk_fma, pk_mul first-iter, exp2-folded branchless
// nonlin, post-barrier OUTBLK, 2-step parity unroll.

#define H      128
#define ENC_T  8192
#define DEC_T  4096
#define NT     512
#define NBLK   1
#define PBV2   4096         // v2f slots per parity: 8 waves * 512

#define LOG2E  1.4426950408889634f

typedef float v2f __attribute__((ext_vector_type(2)));

__device__ __forceinline__ v2f pk_fma_s(v2f a, v2f b_sgpr, v2f c) {
    v2f d;   // b is wave-uniform: read as 64-bit scalar operand (s-pair)
    asm("v_pk_fma_f32 %0, %1, %2, %3" : "=v"(d) : "v"(a), "s"(b_sgpr), "v"(c));
    return d;
}
__device__ __forceinline__ v2f pk_mul_s(v2f a, v2f b_sgpr) {
    v2f d;   // first-iteration accumulator: acc = w*h (no zero-init)
    asm("v_pk_mul_f32 %0, %1, %2" : "=v"(d) : "v"(a), "s"(b_sgpr));
    return d;
}
__device__ __forceinline__ v2f pk_fma(v2f a, v2f b, v2f c) {
    v2f d;
    asm("v_pk_fma_f32 %0, %1, %2, %3" : "=v"(d) : "v"(a), "v"(b), "v"(c));
    return d;
}
__device__ __forceinline__ v2f pk_add(v2f a, v2f b) {
    v2f d;
    asm("v_pk_add_f32 %0, %1, %2" : "=v"(d) : "v"(a), "v"(b));
    return d;
}
__device__ __forceinline__ float exp2fast(float x) {   // raw v_exp_f32 (2^x)
    float d;
    asm("v_exp_f32 %0, %1" : "=v"(d) : "v"(x));
    return d;
}
__device__ __forceinline__ float tanhfast(float x) {   // 1 - 2/(1+2^(2*log2e*x))
    const float e = exp2fast(2.0f * LOG2E * x);
    return fmaf(-2.0f, __builtin_amdgcn_rcpf(1.0f + e), 1.0f);
}
__device__ __forceinline__ float rdlane(float v, int l) {
    return __int_as_float(__builtin_amdgcn_readlane(__float_as_int(v), l));
}
template <int CTRL>
__device__ __forceinline__ float qperm(float v) {      // DPP quad_perm, VALU-speed
    return __int_as_float(
        __builtin_amdgcn_mov_dpp(__float_as_int(v), CTRL, 0xf, 0xf, true));
}

__global__ __launch_bounds__(NT, 2)
void seq2seq_lstm(const float* __restrict__ input_seq,
                  const float* __restrict__ enc_Wih,
                  const float* __restrict__ enc_Whh,
                  const float* __restrict__ enc_bih,
                  const float* __restrict__ enc_bhh,
                  const float* __restrict__ dec_Wih,
                  const float* __restrict__ dec_Whh,
                  const float* __restrict__ dec_bih,
                  const float* __restrict__ dec_bhh,
                  const float* __restrict__ fc_W,
                  const float* __restrict__ fc_b,
                  float* __restrict__ out,
                  unsigned* __restrict__ wsflag)
{
    (void)wsflag;
    __shared__ __align__(16) float xin[ENC_T];          // 32 KB
    __shared__ __align__(16) float hbuf[2][H];          // h history (off-path)
    __shared__ __align__(16) v2f   part2[2][PBV2];      // dbl-buffered raw v2f

    const int t    = threadIdx.x;      // 0..511
    const int lane = t & 63;
    const int wv   = t >> 6;           // wave 0..7, j-slice [16wv,16wv+16)
    const int jb   = 16 * wv;
    const int qq   = lane >> 2;        // reduce role: unit-in-slice 0..15
    const int g    = lane & 3;         // gate 0=i 1=f 2=g 3=o
    const int myu  = jb + qq;          // my unit (global)
    const int myrow = g * H + myu;     // my gate row

    // raw-v2f exchange: slot(w, row=64s+l) = 512w + 64s + l
    const int sr = myrow >> 6;                      // reader row-high
    const int lr = myrow & 63;                      // reader row-low
    const int rbase = 64 * sr + lr;                 // + 512w via imm offset
    const int wbase = 512 * wv + lane;              // + 64s via imm offset

    // branchless nonlin constants (log2e pre-folded):
    // g==2 -> tanh-form, else sigmoid-form
    const float sA  = (g == 2) ? 1.0f : 0.0f;
    const float sB  = (g == 2) ? -2.0f : 1.0f;
    const float sS2 = ((g == 2) ? 2.0f : -1.0f) * LOG2E;

    {   // stage input sequence
        const float4* s = (const float4*)input_seq;
        float4* d = (float4*)xin;
        for (int i = t; i < ENC_T / 4; i += NT) d[i] = s[i];
    }

    // matvec weights as j-pairs: w2[s][jj] = Whh[(64s+lane)][jb+2jj, jb+2jj+1]
    v2f w2[8][8];
#pragma unroll
    for (int s = 0; s < 8; ++s) {
        const v2f* Wr = (const v2f*)(enc_Whh + (64 * s + lane) * H + jb);
#pragma unroll
        for (int jj = 0; jj < 8; ++jj) w2[s][jj] = Wr[jj];
    }
    float bias_r = enc_bih[myrow] + enc_bhh[myrow];
    float wih_r  = enc_Wih[myrow];

    float cst = 0.f;      // cell state of unit myu (replicated per quad)
    float hn  = 0.f;      // h of unit myu (replicated per quad)
    __syncthreads();

    // h[jb+2jj+c] lives in quad 2jj+c of this wave -> g==3 lane 8jj+4c+3
    // row 64s+lane -> raw v2f at wbase + 64s
#define MATVEC(PB)                                                          \
    {                                                                       \
        v2f acc2[8];                                                        \
        {   /* jj = 0: pk_mul, no accumulator init */                       \
            const float se = rdlane(hn, 3);                                 \
            const float so = rdlane(hn, 7);                                 \
            const v2f hp = {se, so};                                        \
            _Pragma("unroll") for (int s = 0; s < 8; ++s)                   \
                acc2[s] = pk_mul_s(w2[s][0], hp);                           \
        }                                                                   \
        _Pragma("unroll") for (int jj = 1; jj < 8; ++jj) {                  \
            const float se = rdlane(hn, 8 * jj + 3);                        \
            const float so = rdlane(hn, 8 * jj + 7);                        \
            const v2f hp = {se, so};                                        \
            _Pragma("unroll") for (int s = 0; s < 8; ++s)                   \
                acc2[s] = pk_fma_s(w2[s][jj], hp, acc2[s]);                 \
        }                                                                   \
        v2f* pb_ = &part2[PB][wbase];                                       \
        _Pragma("unroll") for (int s = 0; s < 8; ++s)                       \
            pb_[64 * s] = acc2[s];                                          \
    }

    // 8x ds_read_b64 (imm offsets 512w), raw v2f partials
#define RED_LOAD(PB)                                                        \
    const v2f* rb_ = &part2[PB][rbase];                                     \
    const v2f q0_ = rb_[0],    q1_ = rb_[512],  q2_ = rb_[1024],            \
              q3_ = rb_[1536], q4_ = rb_[2048], q5_ = rb_[2560],            \
              q6_ = rb_[3072], q7_ = rb_[3584];

    // STH: 1 -> store h to hbuf[PB] (decoder out reads stale hbuf)
#define RED_FIN(PB, ABASE, STH)                                             \
    {                                                                       \
        const v2f tt = pk_add(pk_add(pk_add(q0_, q1_), pk_add(q2_, q3_)),   \
                              pk_add(pk_add(q4_, q5_), pk_add(q6_, q7_)));  \
        const float a = ((ABASE) + tt.x) + tt.y;                            \
        const float e = exp2fast(sS2 * a);                                  \
        const float r = __builtin_amdgcn_rcpf(1.0f + e);                    \
        const float v = fmaf(sB, r, sA);                                    \
        const float vi = qperm<0x00>(v);   /* quad lane 0 */                \
        const float vf = qperm<0x55>(v);   /* quad lane 1 */                \
        const float vg = qperm<0xAA>(v);   /* quad lane 2 */                \
        const float vo = qperm<0xFF>(v);   /* quad lane 3 */                \
        cst = fmaf(vf, cst, vi * vg);                                       \
        hn  = vo * tanhfast(cst);                                           \
        if (STH && g == 3) hbuf[PB][myu] = hn;                              \
    }

    // post-barrier fc output: out[ST-1] from hbuf[HB] (= h after step ST-1;
    // stable: this step's REDUCE writes hbuf[1-HB]). Runs in wave 7's
    // part-read latency shadow.
#define OUTBLK(ST, HB)                                                      \
    if (wv == 7 && (ST) >= 1) {                                             \
        float p = fmaf(fwl, hbuf[HB][lane], fwh * hbuf[HB][64 + lane]);     \
        p += qperm<0xB1>(p);               /* xor 1 */                      \
        p += qperm<0x4E>(p);               /* xor 2 */                      \
        _Pragma("unroll") for (int m = 32; m >= 4; m >>= 1)                 \
            p += __shfl_xor(p, m, 64);                                      \
        if (lane == 0) out[(ST) - 1] = p + fcb;                             \
    }

    // ---------------- encoder: 8192 steps, ONE barrier each ----------------
    for (int st = 0; st < ENC_T; st += 2) {
        const float2 xx = *(const float2*)&xin[st];
        {
            MATVEC(0);
            __syncthreads();
            RED_LOAD(0);
            RED_FIN(0, fmaf(wih_r, xx.x, bias_r), 0);
        }
        {
            MATVEC(1);
            __syncthreads();
            RED_LOAD(1);
            RED_FIN(1, fmaf(wih_r, xx.y, bias_r), 0);
        }
    }
    if (g == 3) hbuf[1][myu] = hn;         // final encoder h, once

    // ---------------- decoder setup: fold fc into Whh ----------------
    const float fcb = fc_b[0];
    const float fwl = fc_W[lane];
    const float fwh = fc_W[64 + lane];
#pragma unroll
    for (int s = 0; s < 8; ++s) {
        const int r = 64 * s + lane;
        const float vi = dec_Wih[r];
        const v2f vip = {vi, vi};
        const v2f* Wr = (const v2f*)(dec_Whh + r * H + jb);
        const v2f* Fr = (const v2f*)(fc_W + jb);
#pragma unroll
        for (int jj = 0; jj < 8; ++jj)
            w2[s][jj] = pk_fma(vip, Fr[jj], Wr[jj]);   // W' = Whh + wih (x) fcW
    }
    wih_r  = dec_Wih[myrow];
    bias_r = dec_bih[myrow] + dec_bhh[myrow] + wih_r * fcb;
    __syncthreads();                       // h_enc visible in hbuf[1]
    float q0;
    {
        float p = fmaf(fwl, hbuf[1][lane], fwh * hbuf[1][64 + lane]);
        p += qperm<0xB1>(p);               // xor 1
        p += qperm<0x4E>(p);               // xor 2
#pragma unroll
        for (int m = 32; m >= 4; m >>= 1) p += __shfl_xor(p, m, 64);
        q0 = p + fcb;
    }
    float cb = bias_r - wih_r * q0;        // step-0 correction (y0 = 0)

    // ---------------- decoder: 4096 steps ----------------
    for (int st = 0; st < DEC_T; st += 2) {
        {   // even step ST=st: out[st-1] from hbuf[1] (odd-parity h)
            MATVEC(0);
            __syncthreads();
            RED_LOAD(0);
            OUTBLK(st, 1);
            RED_FIN(0, cb, 1);
            cb = bias_r;
        }
        {   // odd step ST=st+1: out[st] from hbuf[0]
            MATVEC(1);
            __syncthreads();
            RED_LOAD(1);
            OUTBLK(st + 1, 0);
            RED_FIN(1, cb, 1);
        }
    }

    // tail: out[DEC_T-1] from hbuf[1] (h after final step, parity 1)
    __syncthreads();
    if (wv == 7) {
        float p = fmaf(fwl, hbuf[1][lane], fwh * hbuf[1][64 + lane]);
        p += qperm<0xB1>(p);
        p += qperm<0x4E>(p);
#pragma unroll
        for (int m = 32; m >= 4; m >>= 1) p += __shfl_xor(p, m, 64);
        if (lane == 0) out[DEC_T - 1] = p + fcb;
    }
}

extern "C" void kernel_launch(void* const* d_in, const int* in_sizes, int n_in,
                              void* d_out, int out_size, void* d_ws, size_t ws_size,
                              hipStream_t stream)
{
    (void)in_sizes; (void)n_in; (void)ws_size; (void)out_size;
    seq2seq_lstm<<<NBLK, NT, 0, stream>>>(
        (const float*)d_in[0],   // input_seq
        (const float*)d_in[1],   // enc_Wih
        (const float*)d_in[2],   // enc_Whh
        (const float*)d_in[3],   // enc_bih
        (const float*)d_in[4],   // enc_bhh
        (const float*)d_in[5],   // dec_Wih
        (const float*)d_in[6],   // dec_Whh
        (const float*)d_in[7],   // dec_bih
        (const float*)d_in[8],   // dec_bhh
        (const float*)d_in[9],   // fc_W
        (const float*)d_in[10],  // fc_b
        (float*)d_out,
        (unsigned*)d_ws);
}

// Round 11
// 8041.227 us; speedup vs baseline: 1.4811x; 1.2864x over previous
//
#include <hip/hip_runtime.h>

// Seq2Seq LSTM H=128: enc 8192 + dec 4096 strictly sequential steps.
// Single block, one CU, 512 threads (8 waves). ONE barrier per step.
//
// R19. R18 post-mortem: b64 exchange -> 9.4M bank conflicts (768/step,
// REAL cost, +39% time). Wide LDS ops in this exchange always alias;
// reverted to R16's 8x b32 / 8x b32 scheme (7460 us verified).
// Structure audit: 16-unit/16-j waves are the unique wave-local-h
// point (32-j forces cross-wave h + 2nd barrier; gate-packing = R17
// fail; fewer waves = latency exposure; LDS atomics = CAS x2; wider
// LDS ops = conflicts). Exchange shape is at its local optimum.
//
// R19 change vs R16 — s-outer MATVEC, spread the writes:
//  * All 16 rdlanes hoisted into 8 resident SGPR pairs up front.
//  * Loop s-outer/jj-inner: row s's ds_write_b32 issues right after
//    its 8-deep pk_fma chain completes -- writes spread across the
//    MATVEC window instead of bunching at the end, so the pre-barrier
//    lgkmcnt(0) drain finds an almost-empty LDS queue (~-30-50 cyc).
//  * Instruction count identical; numerics bit-identical.
// Kept from R16: transposed exchange (reader 8x b32 stride-640 imm,
// 2-way banks; writer 8x b32 2-way), s-pair pk_fma, pk_mul first
// iter, exp2-folded branchless nonlin, post-barrier OUTBLK, 2-step
// parity unroll.

#define H      128
#define ENC_T  8192
#define DEC_T  4096
#define NT     512
#define NBLK   1
#define PBUF   5120         // floats per parity: slot max 5103

#define LOG2E  1.4426950408889634f

typedef float v2f __attribute__((ext_vector_type(2)));

__device__ __forceinline__ v2f pk_fma_s(v2f a, v2f b_sgpr, v2f c) {
    v2f d;   // b is wave-uniform: read as 64-bit scalar operand (s-pair)
    asm("v_pk_fma_f32 %0, %1, %2, %3" : "=v"(d) : "v"(a), "s"(b_sgpr), "v"(c));
    return d;
}
__device__ __forceinline__ v2f pk_mul_s(v2f a, v2f b_sgpr) {
    v2f d;   // first-iteration accumulator: acc = w*h (no zero-init)
    asm("v_pk_mul_f32 %0, %1, %2" : "=v"(d) : "v"(a), "s"(b_sgpr));
    return d;
}
__device__ __forceinline__ v2f pk_fma(v2f a, v2f b, v2f c) {
    v2f d;
    asm("v_pk_fma_f32 %0, %1, %2, %3" : "=v"(d) : "v"(a), "v"(b), "v"(c));
    return d;
}
__device__ __forceinline__ float exp2fast(float x) {   // raw v_exp_f32 (2^x)
    float d;
    asm("v_exp_f32 %0, %1" : "=v"(d) : "v"(x));
    return d;
}
__device__ __forceinline__ float tanhfast(float x) {   // 1 - 2/(1+2^(2*log2e*x))
    const float e = exp2fast(2.0f * LOG2E * x);
    return fmaf(-2.0f, __builtin_amdgcn_rcpf(1.0f + e), 1.0f);
}
__device__ __forceinline__ float rdlane(float v, int l) {
    return __int_as_float(__builtin_amdgcn_readlane(__float_as_int(v), l));
}
template <int CTRL>
__device__ __forceinline__ float qperm(float v) {      // DPP quad_perm, VALU-speed
    return __int_as_float(
        __builtin_amdgcn_mov_dpp(__float_as_int(v), CTRL, 0xf, 0xf, true));
}

__global__ __launch_bounds__(NT, 2)
void seq2seq_lstm(const float* __restrict__ input_seq,
                  const float* __restrict__ enc_Wih,
                  const float* __restrict__ enc_Whh,
                  const float* __restrict__ enc_bih,
                  const float* __restrict__ enc_bhh,
                  const float* __restrict__ dec_Wih,
                  const float* __restrict__ dec_Whh,
                  const float* __restrict__ dec_bih,
                  const float* __restrict__ dec_bhh,
                  const float* __restrict__ fc_W,
                  const float* __restrict__ fc_b,
                  float* __restrict__ out,
                  unsigned* __restrict__ wsflag)
{
    (void)wsflag;
    __shared__ __align__(16) float xin[ENC_T];          // 32 KB
    __shared__ __align__(16) float hbuf[2][H];          // h history (off-path)
    __shared__ __align__(16) float part[2][PBUF];       // dbl-buffered partials

    const int t    = threadIdx.x;      // 0..511
    const int lane = t & 63;
    const int wv   = t >> 6;           // wave 0..7, j-slice [16wv,16wv+16)
    const int jb   = 16 * wv;
    const int qq   = lane >> 2;        // reduce role: unit-in-slice 0..15
    const int g    = lane & 3;         // gate 0=i 1=f 2=g 3=o
    const int myu  = jb + qq;          // my unit (global)
    const int myrow = g * H + myu;     // my gate row

    // transposed exchange: slot(w,row) = 640w + 80*(u>>4) + 16*g + (u&15)
    const int rbase = 80 * wv + 16 * g + qq;            // reader base (w=0)
    const int wbase = 640 * wv + 80 * (lane >> 4) + (lane & 15); // writer base

    // branchless nonlin constants (log2e pre-folded):
    // g==2 -> tanh-form, else sigmoid-form
    const float sA  = (g == 2) ? 1.0f : 0.0f;
    const float sB  = (g == 2) ? -2.0f : 1.0f;
    const float sS2 = ((g == 2) ? 2.0f : -1.0f) * LOG2E;

    {   // stage input sequence
        const float4* s = (const float4*)input_seq;
        float4* d = (float4*)xin;
        for (int i = t; i < ENC_T / 4; i += NT) d[i] = s[i];
    }

    // matvec weights as j-pairs: w2[s][jj] = Whh[(64s+lane)][jb+2jj, jb+2jj+1]
    v2f w2[8][8];
#pragma unroll
    for (int s = 0; s < 8; ++s) {
        const v2f* Wr = (const v2f*)(enc_Whh + (64 * s + lane) * H + jb);
#pragma unroll
        for (int jj = 0; jj < 8; ++jj) w2[s][jj] = Wr[jj];
    }
    float bias_r = enc_bih[myrow] + enc_bhh[myrow];
    float wih_r  = enc_Wih[myrow];

    float cst = 0.f;      // cell state of unit myu (replicated per quad)
    float hn  = 0.f;      // h of unit myu (replicated per quad)
    __syncthreads();

    // h[jb+2jj+c] lives in quad 2jj+c of this wave -> g==3 lane 8jj+4c+3
    // row 64s+lane -> slot wbase + 320(s&1) + 16(s>>1)
    // s-outer: each row's write issues as soon as its chain completes.
#define MATVEC(PB)                                                          \
    {                                                                       \
        v2f hp[8];                                                          \
        _Pragma("unroll") for (int jj = 0; jj < 8; ++jj) {                  \
            const float se = rdlane(hn, 8 * jj + 3);                        \
            const float so = rdlane(hn, 8 * jj + 7);                        \
            hp[jj].x = se; hp[jj].y = so;                                   \
        }                                                                   \
        float* pb_ = &part[PB][wbase];                                      \
        _Pragma("unroll") for (int s = 0; s < 8; ++s) {                     \
            v2f acc = pk_mul_s(w2[s][0], hp[0]);                            \
            _Pragma("unroll") for (int jj = 1; jj < 8; ++jj)                \
                acc = pk_fma_s(w2[s][jj], hp[jj], acc);                     \
            pb_[320 * (s & 1) + 16 * (s >> 1)] = acc.x + acc.y;             \
        }                                                                   \
    }

    // 8x conflict-free ds_read_b32 (imm offsets 640w), 7-add tree
#define RED_LOAD(PB)                                                        \
    const float* rb_ = &part[PB][rbase];                                    \
    const float r0_ = rb_[0],    r1_ = rb_[640],  r2_ = rb_[1280],          \
                r3_ = rb_[1920], r4_ = rb_[2560], r5_ = rb_[3200],          \
                r6_ = rb_[3840], r7_ = rb_[4480];

    // STH: 1 -> store h to hbuf[PB] (decoder out reads stale hbuf)
#define RED_FIN(PB, ABASE, STH)                                             \
    {                                                                       \
        const float a = (ABASE) + (((r0_ + r1_) + (r2_ + r3_)) +            \
                                   ((r4_ + r5_) + (r6_ + r7_)));            \
        const float e = exp2fast(sS2 * a);                                  \
        const float r = __builtin_amdgcn_rcpf(1.0f + e);                    \
        const float v = fmaf(sB, r, sA);                                    \
        const float vi = qperm<0x00>(v);   /* quad lane 0 */                \
        const float vf = qperm<0x55>(v);   /* quad lane 1 */                \
        const float vg = qperm<0xAA>(v);   /* quad lane 2 */                \
        const float vo = qperm<0xFF>(v);   /* quad lane 3 */                \
        cst = fmaf(vf, cst, vi * vg);                                       \
        hn  = vo * tanhfast(cst);                                           \
        if (STH && g == 3) hbuf[PB][myu] = hn;                              \
    }

    // post-barrier fc output: out[ST-1] from hbuf[HB] (= h after step ST-1;
    // stable: this step's REDUCE writes hbuf[1-HB]). Runs in wave 7's
    // part-read latency shadow.
#define OUTBLK(ST, HB)                                                      \
    if (wv == 7 && (ST) >= 1) {                                             \
        float p = fmaf(fwl, hbuf[HB][lane], fwh * hbuf[HB][64 + lane]);     \
        p += qperm<0xB1>(p);               /* xor 1 */                      \
        p += qperm<0x4E>(p);               /* xor 2 */                      \
        _Pragma("unroll") for (int m = 32; m >= 4; m >>= 1)                 \
            p += __shfl_xor(p, m, 64);                                      \
        if (lane == 0) out[(ST) - 1] = p + fcb;                             \
    }

    // ---------------- encoder: 8192 steps, ONE barrier each ----------------
    for (int st = 0; st < ENC_T; st += 2) {
        const float2 xx = *(const float2*)&xin[st];
        {
            MATVEC(0);
            __syncthreads();
            RED_LOAD(0);
            RED_FIN(0, fmaf(wih_r, xx.x, bias_r), 0);
        }
        {
            MATVEC(1);
            __syncthreads();
            RED_LOAD(1);
            RED_FIN(1, fmaf(wih_r, xx.y, bias_r), 0);
        }
    }
    if (g == 3) hbuf[1][myu] = hn;         // final encoder h, once

    // ---------------- decoder setup: fold fc into Whh ----------------
    const float fcb = fc_b[0];
    const float fwl = fc_W[lane];
    const float fwh = fc_W[64 + lane];
#pragma unroll
    for (int s = 0; s < 8; ++s) {
        const int r = 64 * s + lane;
        const float vi = dec_Wih[r];
        const v2f vip = {vi, vi};
        const v2f* Wr = (const v2f*)(dec_Whh + r * H + jb);
        const v2f* Fr = (const v2f*)(fc_W + jb);
#pragma unroll
        for (int jj = 0; jj < 8; ++jj)
            w2[s][jj] = pk_fma(vip, Fr[jj], Wr[jj]);   // W' = Whh + wih (x) fcW
    }
    wih_r  = dec_Wih[myrow];
    bias_r = dec_bih[myrow] + dec_bhh[myrow] + wih_r * fcb;
    __syncthreads();                       // h_enc visible in hbuf[1]
    float q0;
    {
        float p = fmaf(fwl, hbuf[1][lane], fwh * hbuf[1][64 + lane]);
        p += qperm<0xB1>(p);               // xor 1
        p += qperm<0x4E>(p);               // xor 2
#pragma unroll
        for (int m = 32; m >= 4; m >>= 1) p += __shfl_xor(p, m, 64);
        q0 = p + fcb;
    }
    float cb = bias_r - wih_r * q0;        // step-0 correction (y0 = 0)

    // ---------------- decoder: 4096 steps ----------------
    for (int st = 0; st < DEC_T; st += 2) {
        {   // even step ST=st: out[st-1] from hbuf[1] (odd-parity h)
            MATVEC(0);
            __syncthreads();
            RED_LOAD(0);
            OUTBLK(st, 1);
            RED_FIN(0, cb, 1);
            cb = bias_r;
        }
        {   // odd step ST=st+1: out[st] from hbuf[0]
            MATVEC(1);
            __syncthreads();
            RED_LOAD(1);
            OUTBLK(st + 1, 0);
            RED_FIN(1, cb, 1);
        }
    }

    // tail: out[DEC_T-1] from hbuf[1] (h after final step, parity 1)
    __syncthreads();
    if (wv == 7) {
        float p = fmaf(fwl, hbuf[1][lane], fwh * hbuf[1][64 + lane]);
        p += qperm<0xB1>(p);
        p += qperm<0x4E>(p);
#pragma unroll
        for (int m = 32; m >= 4; m >>= 1) p += __shfl_xor(p, m, 64);
        if (lane == 0) out[DEC_T - 1] = p + fcb;
    }
}

extern "C" void kernel_launch(void* const* d_in, const int* in_sizes, int n_in,
                              void* d_out, int out_size, void* d_ws, size_t ws_size,
                              hipStream_t stream)
{
    (void)in_sizes; (void)n_in; (void)ws_size; (void)out_size;
    seq2seq_lstm<<<NBLK, NT, 0, stream>>>(
        (const float*)d_in[0],   // input_seq
        (const float*)d_in[1],   // enc_Wih
        (const float*)d_in[2],   // enc_Whh
        (const float*)d_in[3],   // enc_bih
        (const float*)d_in[4],   // enc_bhh
        (const float*)d_in[5],   // dec_Wih
        (const float*)d_in[6],   // dec_Whh
        (const float*)d_in[7],   // dec_bih
        (const float*)d_in[8],   // dec_bhh
        (const float*)d_in[9],   // fc_W
        (const float*)d_in[10],  // fc_b
        (float*)d_out,
        (unsigned*)d_ws);
}

// Round 12
// 7567.419 us; speedup vs baseline: 1.5739x; 1.0626x over previous
//
#include <hip/hip_runtime.h>

// Seq2Seq LSTM H=128: enc 8192 + dec 4096 strictly sequential steps.
// Single block, one CU, 512 threads (8 waves). ONE barrier per step.
//
// R20. R19 post-mortem: s-outer MATVEC = 8 serialized 8-deep dependent
// pk_fma chains (ILP=1) -> +7.6% despite better write spread. R16's
// jj-outer = 8 independent chains (ILP=8) sustains issue rate.
//
// R20 = R16 + HALF-SPLIT MATVEC (both properties):
//  * Two groups of 4 accumulators, each jj-outer (ILP=4; dependent
//    reuse at 8-cyc cadence covers ~4-6 cyc pk_fma latency, plus the
//    co-resident 2nd wave interleaves).
//  * Group 0 (s=0..3) issues its 4 ds_write_b32 at ~50% of the MATVEC
//    window; group 1 at the end -> half the writes get ~250 cyc of
//    drain overlap before the pre-barrier lgkmcnt(0).
//  * rdlanes hoisted once (shared by both halves). Numerics identical
//    to R16.
// Kept from R16: transposed exchange slot(w,row)=640w+80(u>>4)+16g+
// (u&15) (reader 8x b32 stride-640 imm 2-way; writer 8x b32 2-way),
// s-pair pk_fma, pk_mul first-iter, exp2-folded branchless nonlin,
// post-barrier OUTBLK, 2-step parity unroll.
//
// Closed directions (verified): LDS atomics (R12/R15: CAS lowering),
// b64/b128 exchange ops (R14/R18: conflict-invariant or 4-8-way real),
// 4-wave/gate-packing (R17: 256-arch-VGPR cap + latency exposure),
// s-outer (R19: ILP collapse).

#define H      128
#define ENC_T  8192
#define DEC_T  4096
#define NT     512
#define NBLK   1
#define PBUF   5120         // floats per parity: slot max 5103

#define LOG2E  1.4426950408889634f

typedef float v2f __attribute__((ext_vector_type(2)));

__device__ __forceinline__ v2f pk_fma_s(v2f a, v2f b_sgpr, v2f c) {
    v2f d;   // b is wave-uniform: read as 64-bit scalar operand (s-pair)
    asm("v_pk_fma_f32 %0, %1, %2, %3" : "=v"(d) : "v"(a), "s"(b_sgpr), "v"(c));
    return d;
}
__device__ __forceinline__ v2f pk_mul_s(v2f a, v2f b_sgpr) {
    v2f d;   // first-iteration accumulator: acc = w*h (no zero-init)
    asm("v_pk_mul_f32 %0, %1, %2" : "=v"(d) : "v"(a), "s"(b_sgpr));
    return d;
}
__device__ __forceinline__ v2f pk_fma(v2f a, v2f b, v2f c) {
    v2f d;
    asm("v_pk_fma_f32 %0, %1, %2, %3" : "=v"(d) : "v"(a), "v"(b), "v"(c));
    return d;
}
__device__ __forceinline__ float exp2fast(float x) {   // raw v_exp_f32 (2^x)
    float d;
    asm("v_exp_f32 %0, %1" : "=v"(d) : "v"(x));
    return d;
}
__device__ __forceinline__ float tanhfast(float x) {   // 1 - 2/(1+2^(2*log2e*x))
    const float e = exp2fast(2.0f * LOG2E * x);
    return fmaf(-2.0f, __builtin_amdgcn_rcpf(1.0f + e), 1.0f);
}
__device__ __forceinline__ float rdlane(float v, int l) {
    return __int_as_float(__builtin_amdgcn_readlane(__float_as_int(v), l));
}
template <int CTRL>
__device__ __forceinline__ float qperm(float v) {      // DPP quad_perm, VALU-speed
    return __int_as_float(
        __builtin_amdgcn_mov_dpp(__float_as_int(v), CTRL, 0xf, 0xf, true));
}

__global__ __launch_bounds__(NT, 2)
void seq2seq_lstm(const float* __restrict__ input_seq,
                  const float* __restrict__ enc_Wih,
                  const float* __restrict__ enc_Whh,
                  const float* __restrict__ enc_bih,
                  const float* __restrict__ enc_bhh,
                  const float* __restrict__ dec_Wih,
                  const float* __restrict__ dec_Whh,
                  const float* __restrict__ dec_bih,
                  const float* __restrict__ dec_bhh,
                  const float* __restrict__ fc_W,
                  const float* __restrict__ fc_b,
                  float* __restrict__ out,
                  unsigned* __restrict__ wsflag)
{
    (void)wsflag;
    __shared__ __align__(16) float xin[ENC_T];          // 32 KB
    __shared__ __align__(16) float hbuf[2][H];          // h history (off-path)
    __shared__ __align__(16) float part[2][PBUF];       // dbl-buffered partials

    const int t    = threadIdx.x;      // 0..511
    const int lane = t & 63;
    const int wv   = t >> 6;           // wave 0..7, j-slice [16wv,16wv+16)
    const int jb   = 16 * wv;
    const int qq   = lane >> 2;        // reduce role: unit-in-slice 0..15
    const int g    = lane & 3;         // gate 0=i 1=f 2=g 3=o
    const int myu  = jb + qq;          // my unit (global)
    const int myrow = g * H + myu;     // my gate row

    // transposed exchange: slot(w,row) = 640w + 80*(u>>4) + 16*g + (u&15)
    const int rbase = 80 * wv + 16 * g + qq;            // reader base (w=0)
    const int wbase = 640 * wv + 80 * (lane >> 4) + (lane & 15); // writer base

    // branchless nonlin constants (log2e pre-folded):
    // g==2 -> tanh-form, else sigmoid-form
    const float sA  = (g == 2) ? 1.0f : 0.0f;
    const float sB  = (g == 2) ? -2.0f : 1.0f;
    const float sS2 = ((g == 2) ? 2.0f : -1.0f) * LOG2E;

    {   // stage input sequence
        const float4* s = (const float4*)input_seq;
        float4* d = (float4*)xin;
        for (int i = t; i < ENC_T / 4; i += NT) d[i] = s[i];
    }

    // matvec weights as j-pairs: w2[s][jj] = Whh[(64s+lane)][jb+2jj, jb+2jj+1]
    v2f w2[8][8];
#pragma unroll
    for (int s = 0; s < 8; ++s) {
        const v2f* Wr = (const v2f*)(enc_Whh + (64 * s + lane) * H + jb);
#pragma unroll
        for (int jj = 0; jj < 8; ++jj) w2[s][jj] = Wr[jj];
    }
    float bias_r = enc_bih[myrow] + enc_bhh[myrow];
    float wih_r  = enc_Wih[myrow];

    float cst = 0.f;      // cell state of unit myu (replicated per quad)
    float hn  = 0.f;      // h of unit myu (replicated per quad)
    __syncthreads();

    // h[jb+2jj+c] lives in quad 2jj+c of this wave -> g==3 lane 8jj+4c+3
    // row 64s+lane -> slot wbase + 320(s&1) + 16(s>>1)
    // Half-split: group 0 = s 0..3 (writes at ~50% of window), group 1 =
    // s 4..7 (writes at end). Each group jj-outer (ILP=4).
#define MATVEC(PB)                                                          \
    {                                                                       \
        v2f hp[8];                                                          \
        _Pragma("unroll") for (int jj = 0; jj < 8; ++jj) {                  \
            const float se = rdlane(hn, 8 * jj + 3);                        \
            const float so = rdlane(hn, 8 * jj + 7);                        \
            hp[jj].x = se; hp[jj].y = so;                                   \
        }                                                                   \
        float* pb_ = &part[PB][wbase];                                      \
        {   /* group 0: s = 0..3 */                                         \
            v2f a0 = pk_mul_s(w2[0][0], hp[0]);                             \
            v2f a1 = pk_mul_s(w2[1][0], hp[0]);                             \
            v2f a2 = pk_mul_s(w2[2][0], hp[0]);                             \
            v2f a3 = pk_mul_s(w2[3][0], hp[0]);                             \
            _Pragma("unroll") for (int jj = 1; jj < 8; ++jj) {              \
                a0 = pk_fma_s(w2[0][jj], hp[jj], a0);                       \
                a1 = pk_fma_s(w2[1][jj], hp[jj], a1);                       \
                a2 = pk_fma_s(w2[2][jj], hp[jj], a2);                       \
                a3 = pk_fma_s(w2[3][jj], hp[jj], a3);                       \
            }                                                               \
            pb_[0]   = a0.x + a0.y;                                         \
            pb_[320] = a1.x + a1.y;                                         \
            pb_[16]  = a2.x + a2.y;                                         \
            pb_[336] = a3.x + a3.y;                                         \
        }                                                                   \
        {   /* group 1: s = 4..7 */                                         \
            v2f a4 = pk_mul_s(w2[4][0], hp[0]);                             \
            v2f a5 = pk_mul_s(w2[5][0], hp[0]);                             \
            v2f a6 = pk_mul_s(w2[6][0], hp[0]);                             \
            v2f a7 = pk_mul_s(w2[7][0], hp[0]);                             \
            _Pragma("unroll") for (int jj = 1; jj < 8; ++jj) {              \
                a4 = pk_fma_s(w2[4][jj], hp[jj], a4);                       \
                a5 = pk_fma_s(w2[5][jj], hp[jj], a5);                       \
                a6 = pk_fma_s(w2[6][jj], hp[jj], a6);                       \
                a7 = pk_fma_s(w2[7][jj], hp[jj], a7);                       \
            }                                                               \
            pb_[32]  = a4.x + a4.y;                                         \
            pb_[352] = a5.x + a5.y;                                         \
            pb_[48]  = a6.x + a6.y;                                         \
            pb_[368] = a7.x + a7.y;                                         \
        }                                                                   \
    }

    // 8x conflict-free ds_read_b32 (imm offsets 640w), 7-add tree
#define RED_LOAD(PB)                                                        \
    const float* rb_ = &part[PB][rbase];                                    \
    const float r0_ = rb_[0],    r1_ = rb_[640],  r2_ = rb_[1280],          \
                r3_ = rb_[1920], r4_ = rb_[2560], r5_ = rb_[3200],          \
                r6_ = rb_[3840], r7_ = rb_[4480];

    // STH: 1 -> store h to hbuf[PB] (decoder out reads stale hbuf)
#define RED_FIN(PB, ABASE, STH)                                             \
    {                                                                       \
        const float a = (ABASE) + (((r0_ + r1_) + (r2_ + r3_)) +            \
                                   ((r4_ + r5_) + (r6_ + r7_)));            \
        const float e = exp2fast(sS2 * a);                                  \
        const float r = __builtin_amdgcn_rcpf(1.0f + e);                    \
        const float v = fmaf(sB, r, sA);                                    \
        const float vi = qperm<0x00>(v);   /* quad lane 0 */                \
        const float vf = qperm<0x55>(v);   /* quad lane 1 */                \
        const float vg = qperm<0xAA>(v);   /* quad lane 2 */                \
        const float vo = qperm<0xFF>(v);   /* quad lane 3 */                \
        cst = fmaf(vf, cst, vi * vg);                                       \
        hn  = vo * tanhfast(cst);                                           \
        if (STH && g == 3) hbuf[PB][myu] = hn;                              \
    }

    // post-barrier fc output: out[ST-1] from hbuf[HB] (= h after step ST-1;
    // stable: this step's REDUCE writes hbuf[1-HB]). Runs in wave 7's
    // part-read latency shadow.
#define OUTBLK(ST, HB)                                                      \
    if (wv == 7 && (ST) >= 1) {                                             \
        float p = fmaf(fwl, hbuf[HB][lane], fwh * hbuf[HB][64 + lane]);     \
        p += qperm<0xB1>(p);               /* xor 1 */                      \
        p += qperm<0x4E>(p);               /* xor 2 */                      \
        _Pragma("unroll") for (int m = 32; m >= 4; m >>= 1)                 \
            p += __shfl_xor(p, m, 64);                                      \
        if (lane == 0) out[(ST) - 1] = p + fcb;                             \
    }

    // ---------------- encoder: 8192 steps, ONE barrier each ----------------
    for (int st = 0; st < ENC_T; st += 2) {
        const float2 xx = *(const float2*)&xin[st];
        {
            MATVEC(0);
            __syncthreads();
            RED_LOAD(0);
            RED_FIN(0, fmaf(wih_r, xx.x, bias_r), 0);
        }
        {
            MATVEC(1);
            __syncthreads();
            RED_LOAD(1);
            RED_FIN(1, fmaf(wih_r, xx.y, bias_r), 0);
        }
    }
    if (g == 3) hbuf[1][myu] = hn;         // final encoder h, once

    // ---------------- decoder setup: fold fc into Whh ----------------
    const float fcb = fc_b[0];
    const float fwl = fc_W[lane];
    const float fwh = fc_W[64 + lane];
#pragma unroll
    for (int s = 0; s < 8; ++s) {
        const int r = 64 * s + lane;
        const float vi = dec_Wih[r];
        const v2f vip = {vi, vi};
        const v2f* Wr = (const v2f*)(dec_Whh + r * H + jb);
        const v2f* Fr = (const v2f*)(fc_W + jb);
#pragma unroll
        for (int jj = 0; jj < 8; ++jj)
            w2[s][jj] = pk_fma(vip, Fr[jj], Wr[jj]);   // W' = Whh + wih (x) fcW
    }
    wih_r  = dec_Wih[myrow];
    bias_r = dec_bih[myrow] + dec_bhh[myrow] + wih_r * fcb;
    __syncthreads();                       // h_enc visible in hbuf[1]
    float q0;
    {
        float p = fmaf(fwl, hbuf[1][lane], fwh * hbuf[1][64 + lane]);
        p += qperm<0xB1>(p);               // xor 1
        p += qperm<0x4E>(p);               // xor 2
#pragma unroll
        for (int m = 32; m >= 4; m >>= 1) p += __shfl_xor(p, m, 64);
        q0 = p + fcb;
    }
    float cb = bias_r - wih_r * q0;        // step-0 correction (y0 = 0)

    // ---------------- decoder: 4096 steps ----------------
    for (int st = 0; st < DEC_T; st += 2) {
        {   // even step ST=st: out[st-1] from hbuf[1] (odd-parity h)
            MATVEC(0);
            __syncthreads();
            RED_LOAD(0);
            OUTBLK(st, 1);
            RED_FIN(0, cb, 1);
            cb = bias_r;
        }
        {   // odd step ST=st+1: out[st] from hbuf[0]
            MATVEC(1);
            __syncthreads();
            RED_LOAD(1);
            OUTBLK(st + 1, 0);
            RED_FIN(1, cb, 1);
        }
    }

    // tail: out[DEC_T-1] from hbuf[1] (h after final step, parity 1)
    __syncthreads();
    if (wv == 7) {
        float p = fmaf(fwl, hbuf[1][lane], fwh * hbuf[1][64 + lane]);
        p += qperm<0xB1>(p);
        p += qperm<0x4E>(p);
#pragma unroll
        for (int m = 32; m >= 4; m >>= 1) p += __shfl_xor(p, m, 64);
        if (lane == 0) out[DEC_T - 1] = p + fcb;
    }
}

extern "C" void kernel_launch(void* const* d_in, const int* in_sizes, int n_in,
                              void* d_out, int out_size, void* d_ws, size_t ws_size,
                              hipStream_t stream)
{
    (void)in_sizes; (void)n_in; (void)ws_size; (void)out_size;
    seq2seq_lstm<<<NBLK, NT, 0, stream>>>(
        (const float*)d_in[0],   // input_seq
        (const float*)d_in[1],   // enc_Wih
        (const float*)d_in[2],   // enc_Whh
        (const float*)d_in[3],   // enc_bih
        (const float*)d_in[4],   // enc_bhh
        (const float*)d_in[5],   // dec_Wih
        (const float*)d_in[6],   // dec_Whh
        (const float*)d_in[7],   // dec_bih
        (const float*)d_in[8],   // dec_bhh
        (const float*)d_in[9],   // fc_W
        (const float*)d_in[10],  // fc_b
        (float*)d_out,
        (unsigned*)d_ws);
}

// Round 13
// 7494.973 us; speedup vs baseline: 1.5891x; 1.0097x over previous
//
#include <hip/hip_runtime.h>

// Seq2Seq LSTM H=128: enc 8192 + dec 4096 strictly sequential steps.
// Single block, one CU, 512 threads (8 waves). ONE barrier per step.
//
// R21 = exact revert to R16 (best verified: 7460 us steady, 990
// cyc/step @1.63GHz). R20's half-split MATVEC was +0.9% -> the
// pre-barrier drain was already ~free; reverted.
//
// Final structure and its measured budget:
//   256 cyc  pk_fma MAC floor (65536 MAC/step, 2 waves/SIMD, pk=2/lane)
//  ~260 cyc  minimal exchange + nonlin + readlane issue
//  ~280 cyc  serial post-barrier chain (ds_read ~120 + 7-add tree +
//            gate exp/rcp chain + qperm + cst/tanh chain)
//  ~190 cyc  barrier + inter-wave skew
//
// Closed directions (all measured): LDS float atomics (R12/R15: CAS
// lowering, 12x), b64/b128 exchange (R14/R18: conflict-invariant /
// 4-8-way real, +39%), conflict swizzles (R14: invariant at the
// 2-lanes/bank floor), 4-wave+gate-packing (R17: 256-arch-VGPR cap +
// latency exposure, +59%), s-outer (R19: ILP collapse, +7.6%),
// half-split (R20: +0.9%). Wins kept: s-pair pk_fma operands, packed
// conflict-free transposed exchange, pk_mul first-iter, exp2-folded
// branchless nonlin, post-barrier OUTBLK, 2-step parity unroll.

#define H      128
#define ENC_T  8192
#define DEC_T  4096
#define NT     512
#define NBLK   1
#define PBUF   5120         // floats per parity: slot max 5103

#define LOG2E  1.4426950408889634f

typedef float v2f __attribute__((ext_vector_type(2)));

__device__ __forceinline__ v2f pk_fma_s(v2f a, v2f b_sgpr, v2f c) {
    v2f d;   // b is wave-uniform: read as 64-bit scalar operand (s-pair)
    asm("v_pk_fma_f32 %0, %1, %2, %3" : "=v"(d) : "v"(a), "s"(b_sgpr), "v"(c));
    return d;
}
__device__ __forceinline__ v2f pk_mul_s(v2f a, v2f b_sgpr) {
    v2f d;   // first-iteration accumulator: acc = w*h (no zero-init)
    asm("v_pk_mul_f32 %0, %1, %2" : "=v"(d) : "v"(a), "s"(b_sgpr));
    return d;
}
__device__ __forceinline__ v2f pk_fma(v2f a, v2f b, v2f c) {
    v2f d;
    asm("v_pk_fma_f32 %0, %1, %2, %3" : "=v"(d) : "v"(a), "v"(b), "v"(c));
    return d;
}
__device__ __forceinline__ float exp2fast(float x) {   // raw v_exp_f32 (2^x)
    float d;
    asm("v_exp_f32 %0, %1" : "=v"(d) : "v"(x));
    return d;
}
__device__ __forceinline__ float tanhfast(float x) {   // 1 - 2/(1+2^(2*log2e*x))
    const float e = exp2fast(2.0f * LOG2E * x);
    return fmaf(-2.0f, __builtin_amdgcn_rcpf(1.0f + e), 1.0f);
}
__device__ __forceinline__ float rdlane(float v, int l) {
    return __int_as_float(__builtin_amdgcn_readlane(__float_as_int(v), l));
}
template <int CTRL>
__device__ __forceinline__ float qperm(float v) {      // DPP quad_perm, VALU-speed
    return __int_as_float(
        __builtin_amdgcn_mov_dpp(__float_as_int(v), CTRL, 0xf, 0xf, true));
}

__global__ __launch_bounds__(NT, 2)
void seq2seq_lstm(const float* __restrict__ input_seq,
                  const float* __restrict__ enc_Wih,
                  const float* __restrict__ enc_Whh,
                  const float* __restrict__ enc_bih,
                  const float* __restrict__ enc_bhh,
                  const float* __restrict__ dec_Wih,
                  const float* __restrict__ dec_Whh,
                  const float* __restrict__ dec_bih,
                  const float* __restrict__ dec_bhh,
                  const float* __restrict__ fc_W,
                  const float* __restrict__ fc_b,
                  float* __restrict__ out,
                  unsigned* __restrict__ wsflag)
{
    (void)wsflag;
    __shared__ __align__(16) float xin[ENC_T];          // 32 KB
    __shared__ __align__(16) float hbuf[2][H];          // h history (off-path)
    __shared__ __align__(16) float part[2][PBUF];       // dbl-buffered partials

    const int t    = threadIdx.x;      // 0..511
    const int lane = t & 63;
    const int wv   = t >> 6;           // wave 0..7, j-slice [16wv,16wv+16)
    const int jb   = 16 * wv;
    const int qq   = lane >> 2;        // reduce role: unit-in-slice 0..15
    const int g    = lane & 3;         // gate 0=i 1=f 2=g 3=o
    const int myu  = jb + qq;          // my unit (global)
    const int myrow = g * H + myu;     // my gate row

    // transposed exchange: slot(w,row) = 640w + 80*(u>>4) + 16*g + (u&15)
    const int rbase = 80 * wv + 16 * g + qq;            // reader base (w=0)
    const int wbase = 640 * wv + 80 * (lane >> 4) + (lane & 15); // writer base

    // branchless nonlin constants (log2e pre-folded):
    // g==2 -> tanh-form, else sigmoid-form
    const float sA  = (g == 2) ? 1.0f : 0.0f;
    const float sB  = (g == 2) ? -2.0f : 1.0f;
    const float sS2 = ((g == 2) ? 2.0f : -1.0f) * LOG2E;

    {   // stage input sequence
        const float4* s = (const float4*)input_seq;
        float4* d = (float4*)xin;
        for (int i = t; i < ENC_T / 4; i += NT) d[i] = s[i];
    }

    // matvec weights as j-pairs: w2[s][jj] = Whh[(64s+lane)][jb+2jj, jb+2jj+1]
    v2f w2[8][8];
#pragma unroll
    for (int s = 0; s < 8; ++s) {
        const v2f* Wr = (const v2f*)(enc_Whh + (64 * s + lane) * H + jb);
#pragma unroll
        for (int jj = 0; jj < 8; ++jj) w2[s][jj] = Wr[jj];
    }
    float bias_r = enc_bih[myrow] + enc_bhh[myrow];
    float wih_r  = enc_Wih[myrow];

    float cst = 0.f;      // cell state of unit myu (replicated per quad)
    float hn  = 0.f;      // h of unit myu (replicated per quad)
    __syncthreads();

    // h[jb+2jj+c] lives in quad 2jj+c of this wave -> g==3 lane 8jj+4c+3
#define MATVEC(PB)                                                          \
    {                                                                       \
        v2f acc2[8];                                                        \
        {   /* jj = 0: pk_mul, no accumulator init */                       \
            const float se = rdlane(hn, 3);                                 \
            const float so = rdlane(hn, 7);                                 \
            const v2f hp = {se, so};                                        \
            _Pragma("unroll") for (int s = 0; s < 8; ++s)                   \
                acc2[s] = pk_mul_s(w2[s][0], hp);                           \
        }                                                                   \
        _Pragma("unroll") for (int jj = 1; jj < 8; ++jj) {                  \
            const float se = rdlane(hn, 8 * jj + 3);                        \
            const float so = rdlane(hn, 8 * jj + 7);                        \
            const v2f hp = {se, so};                                        \
            _Pragma("unroll") for (int s = 0; s < 8; ++s)                   \
                acc2[s] = pk_fma_s(w2[s][jj], hp, acc2[s]);                 \
        }                                                                   \
        float* pb_ = &part[PB][wbase];                                      \
        pb_[0]   = acc2[0].x + acc2[0].y;                                   \
        pb_[320] = acc2[1].x + acc2[1].y;                                   \
        pb_[16]  = acc2[2].x + acc2[2].y;                                   \
        pb_[336] = acc2[3].x + acc2[3].y;                                   \
        pb_[32]  = acc2[4].x + acc2[4].y;                                   \
        pb_[352] = acc2[5].x + acc2[5].y;                                   \
        pb_[48]  = acc2[6].x + acc2[6].y;                                   \
        pb_[368] = acc2[7].x + acc2[7].y;                                   \
    }

    // 8x conflict-free ds_read_b32 (imm offsets 640w), 7-add tree
#define RED_LOAD(PB)                                                        \
    const float* rb_ = &part[PB][rbase];                                    \
    const float r0_ = rb_[0],    r1_ = rb_[640],  r2_ = rb_[1280],          \
                r3_ = rb_[1920], r4_ = rb_[2560], r5_ = rb_[3200],          \
                r6_ = rb_[3840], r7_ = rb_[4480];

    // STH: 1 -> store h to hbuf[PB] (decoder out reads stale hbuf)
#define RED_FIN(PB, ABASE, STH)                                             \
    {                                                                       \
        const float a = (ABASE) + (((r0_ + r1_) + (r2_ + r3_)) +            \
                                   ((r4_ + r5_) + (r6_ + r7_)));            \
        const float e = exp2fast(sS2 * a);                                  \
        const float r = __builtin_amdgcn_rcpf(1.0f + e);                    \
        const float v = fmaf(sB, r, sA);                                    \
        const float vi = qperm<0x00>(v);   /* quad lane 0 */                \
        const float vf = qperm<0x55>(v);   /* quad lane 1 */                \
        const float vg = qperm<0xAA>(v);   /* quad lane 2 */                \
        const float vo = qperm<0xFF>(v);   /* quad lane 3 */                \
        cst = fmaf(vf, cst, vi * vg);                                       \
        hn  = vo * tanhfast(cst);                                           \
        if (STH && g == 3) hbuf[PB][myu] = hn;                              \
    }

    // post-barrier fc output: out[ST-1] from hbuf[HB] (= h after step ST-1;
    // stable: this step's REDUCE writes hbuf[1-HB]). Runs in wave 7's
    // part-read latency shadow.
#define OUTBLK(ST, HB)                                                      \
    if (wv == 7 && (ST) >= 1) {                                             \
        float p = fmaf(fwl, hbuf[HB][lane], fwh * hbuf[HB][64 + lane]);     \
        p += qperm<0xB1>(p);               /* xor 1 */                      \
        p += qperm<0x4E>(p);               /* xor 2 */                      \
        _Pragma("unroll") for (int m = 32; m >= 4; m >>= 1)                 \
            p += __shfl_xor(p, m, 64);                                      \
        if (lane == 0) out[(ST) - 1] = p + fcb;                             \
    }

    // ---------------- encoder: 8192 steps, ONE barrier each ----------------
    for (int st = 0; st < ENC_T; st += 2) {
        const float2 xx = *(const float2*)&xin[st];
        {
            MATVEC(0);
            __syncthreads();
            RED_LOAD(0);
            RED_FIN(0, fmaf(wih_r, xx.x, bias_r), 0);
        }
        {
            MATVEC(1);
            __syncthreads();
            RED_LOAD(1);
            RED_FIN(1, fmaf(wih_r, xx.y, bias_r), 0);
        }
    }
    if (g == 3) hbuf[1][myu] = hn;         // final encoder h, once

    // ---------------- decoder setup: fold fc into Whh ----------------
    const float fcb = fc_b[0];
    const float fwl = fc_W[lane];
    const float fwh = fc_W[64 + lane];
#pragma unroll
    for (int s = 0; s < 8; ++s) {
        const int r = 64 * s + lane;
        const float vi = dec_Wih[r];
        const v2f vip = {vi, vi};
        const v2f* Wr = (const v2f*)(dec_Whh + r * H + jb);
        const v2f* Fr = (const v2f*)(fc_W + jb);
#pragma unroll
        for (int jj = 0; jj < 8; ++jj)
            w2[s][jj] = pk_fma(vip, Fr[jj], Wr[jj]);   // W' = Whh + wih (x) fcW
    }
    wih_r  = dec_Wih[myrow];
    bias_r = dec_bih[myrow] + dec_bhh[myrow] + wih_r * fcb;
    __syncthreads();                       // h_enc visible in hbuf[1]
    float q0;
    {
        float p = fmaf(fwl, hbuf[1][lane], fwh * hbuf[1][64 + lane]);
        p += qperm<0xB1>(p);               // xor 1
        p += qperm<0x4E>(p);               // xor 2
#pragma unroll
        for (int m = 32; m >= 4; m >>= 1) p += __shfl_xor(p, m, 64);
        q0 = p + fcb;
    }
    float cb = bias_r - wih_r * q0;        // step-0 correction (y0 = 0)

    // ---------------- decoder: 4096 steps ----------------
    for (int st = 0; st < DEC_T; st += 2) {
        {   // even step ST=st: out[st-1] from hbuf[1] (odd-parity h)
            MATVEC(0);
            __syncthreads();
            RED_LOAD(0);
            OUTBLK(st, 1);
            RED_FIN(0, cb, 1);
            cb = bias_r;
        }
        {   // odd step ST=st+1: out[st] from hbuf[0]
            MATVEC(1);
            __syncthreads();
            RED_LOAD(1);
            OUTBLK(st + 1, 0);
            RED_FIN(1, cb, 1);
        }
    }

    // tail: out[DEC_T-1] from hbuf[1] (h after final step, parity 1)
    __syncthreads();
    if (wv == 7) {
        float p = fmaf(fwl, hbuf[1][lane], fwh * hbuf[1][64 + lane]);
        p += qperm<0xB1>(p);
        p += qperm<0x4E>(p);
#pragma unroll
        for (int m = 32; m >= 4; m >>= 1) p += __shfl_xor(p, m, 64);
        if (lane == 0) out[DEC_T - 1] = p + fcb;
    }
}

extern "C" void kernel_launch(void* const* d_in, const int* in_sizes, int n_in,
                              void* d_out, int out_size, void* d_ws, size_t ws_size,
                              hipStream_t stream)
{
    (void)in_sizes; (void)n_in; (void)ws_size; (void)out_size;
    seq2seq_lstm<<<NBLK, NT, 0, stream>>>(
        (const float*)d_in[0],   // input_seq
        (const float*)d_in[1],   // enc_Wih
        (const float*)d_in[2],   // enc_Whh
        (const float*)d_in[3],   // enc_bih
        (const float*)d_in[4],   // enc_bhh
        (const float*)d_in[5],   // dec_Wih
        (const float*)d_in[6],   // dec_Whh
        (const float*)d_in[7],   // dec_bih
        (const float*)d_in[8],   // dec_bhh
        (const float*)d_in[9],   // fc_W
        (const float*)d_in[10],  // fc_b
        (float*)d_out,
        (unsigned*)d_ws);
}